// Round 7
// baseline (352.131 us; speedup 1.0000x reference)
//
#include <hip/hip_runtime.h>
#include <hip/hip_bf16.h>

typedef __attribute__((ext_vector_type(4)))  float f32x4;
typedef __attribute__((ext_vector_type(16))) float f32x16;
typedef __attribute__((ext_vector_type(8)))  short bf16x8;
typedef __attribute__((ext_vector_type(4)))  unsigned u32x4;

#define S_LEN 4096
#define HEAD_D 64
#define WIN 256
#define QBLK 128
#define KVBLK 64
#define KSTR 72   // k_lds row stride (shorts): b128 reads hit the 8-round LDS minimum
#define VSTR 72   // vt_lds row stride (shorts), [d][key'] with key' = key bits2<->3 swapped
#define QSCALE 0.18033688f   // log2(e)/8 folded into Q; no numerator shift (scores |s|<~10)

#define KBYTES (KVBLK * KSTR * 2)    // 9216 B per K buffer
#define VBYTES (HEAD_D * VSTR * 2)   // 9216 B per V buffer
// layout: k0@0, k1@KBYTES, vt0@2K, vt1@2K+V | epilogue overlay o_mrg[4][32][64] f32 @0
#define LPAR_OFF (2 * KBYTES + 2 * VBYTES)          // 36864
#define SMEM_BYTES (LPAR_OFF + 2 * 4 * 32 * 4)      // +1KB l partials = 37888

// HW packed f32->bf16 (RNE), 1 instr for 2 values
static __device__ __forceinline__ unsigned cvt2(float lo, float hi) {
  unsigned r;
  asm("v_cvt_pk_bf16_f32 %0, %1, %2" : "=v"(r) : "v"(lo), "v"(hi));
  return r;
}

__global__ __launch_bounds__(512, 8)
void swa_fwd(const float* __restrict__ Q, const float* __restrict__ K,
             const float* __restrict__ V, float* __restrict__ O) {
  __shared__ __attribute__((aligned(16))) char smem[SMEM_BYTES];

  const int tid  = threadIdx.x;
  const int widx = tid >> 6;
  const int lane = tid & 63;
  const int hi   = lane >> 5;
  const int c    = lane & 31;
  const int qg   = widx & 3;    // q-group: 32 rows
  const int kh   = widx >> 2;   // key half of each 64-key tile
  const int kho  = kh * 32;

  // XCD swizzle: 4 contiguous bh per XCD, qb fastest -> neighbor-qb L2 reuse.
  const int pb  = blockIdx.x;
  const int bh  = (pb & 7) * 4 + ((pb >> 3) >> 5);
  const int qb  = (pb >> 3) & 31;
  const int bq0 = qb * QBLK;
  const int q0w = bq0 + qg * 32;

  const size_t base = (size_t)bh * S_LEN * HEAD_D;
  const float* Qp = Q + base;
  const float* Kp = K + base;
  const float* Vp = V + base;
  float*       Op = O + base;

  const f32x16 Z16 = {0.f,0.f,0.f,0.f,0.f,0.f,0.f,0.f,0.f,0.f,0.f,0.f,0.f,0.f,0.f,0.f};

  // ---- Q B-fragments: lane holds Q[q0w+c][ch*16 + hi*8 + j]*QSCALE ----
  bf16x8 aq[4];
  {
    const float* qr = Qp + (size_t)(q0w + c) * HEAD_D + hi * 8;
    #pragma unroll
    for (int ch = 0; ch < 4; ++ch) {
      f32x4 x0 = *(const f32x4*)(qr + ch * 16);
      f32x4 x1 = *(const f32x4*)(qr + ch * 16 + 4);
      u32x4 au;
      au[0] = cvt2(x0[0] * QSCALE, x0[1] * QSCALE);
      au[1] = cvt2(x0[2] * QSCALE, x0[3] * QSCALE);
      au[2] = cvt2(x1[0] * QSCALE, x1[1] * QSCALE);
      au[3] = cvt2(x1[2] * QSCALE, x1[3] * QSCALE);
      aq[ch] = __builtin_bit_cast(bf16x8, au);
    }
  }

  f32x16 acc0 = Z16, acc1 = Z16;   // O-partial [32q x d0-31 / d32-63] for this key-half
  float lsum = 0.f;

  const int lo   = max(0, bq0 - WIN);
  const int khiB = min(S_LEN, bq0 + QBLK + WIN);
  const int nt   = (khiB - lo) >> 6;   // >= 6; multiples of 64; keys always in [0,S)

  // staging: K coalesced rows (8 lanes/row, b128 LDS write);
  // V: thread owns key pair (key2,key2+1) x 4 d, packs 2 keys/one b32 write at permuted col
  const int krow  = tid >> 3;          // 0..63
  const int kc8   = (tid & 7) << 3;    // 0..56
  const int key2  = (tid & 31) << 1;   // 0..62 (even)
  const int key2p = (key2 & ~12) | ((key2 & 4) << 1) | ((key2 & 8) >> 1);  // bits 2<->3
  const int vd4   = (tid >> 5) << 2;   // 0..60
  const float* kpt  = Kp + (size_t)(lo + krow) * HEAD_D + kc8;
  const float* vpt0 = Vp + (size_t)(lo + key2) * HEAD_D + vd4;
  const float* vpt1 = vpt0 + HEAD_D;

  f32x4 ka0, ka1, va0, va1;
  #define LOAD_TILE() do {                         \
    ka0 = *(const f32x4*)kpt;                      \
    ka1 = *(const f32x4*)(kpt + 4);                \
    va0 = *(const f32x4*)vpt0;                     \
    va1 = *(const f32x4*)vpt1;                     \
    kpt  += KVBLK * HEAD_D;                        \
    vpt0 += KVBLK * HEAD_D;                        \
    vpt1 += KVBLK * HEAD_D;                        \
  } while (0)

  #define STAGE_TO(buf) do {                                              \
    short* kb_ = (short*)(smem + (buf) * KBYTES);                         \
    short* vb_ = (short*)(smem + 2 * KBYTES + (buf) * VBYTES);            \
    u32x4 kw;                                                             \
    kw[0] = cvt2(ka0[0], ka0[1]);                                         \
    kw[1] = cvt2(ka0[2], ka0[3]);                                         \
    kw[2] = cvt2(ka1[0], ka1[1]);                                         \
    kw[3] = cvt2(ka1[2], ka1[3]);                                         \
    *(u32x4*)&kb_[krow * KSTR + kc8] = kw;                                \
    _Pragma("unroll")                                                     \
    for (int j = 0; j < 4; ++j)                                           \
      *(unsigned*)&vb_[(vd4 + j) * VSTR + key2p] = cvt2(va0[j], va1[j]);  \
  } while (0)

  // prologue: stage tile 0, prefetch tile 1
  LOAD_TILE();
  STAGE_TO(0);
  LOAD_TILE();
  __syncthreads();

  int cur = 0;
  for (int t = 0; t < nt; ++t) {
    const int kv0 = lo + (t << 6);
    const short* kb = (const short*)(smem + cur * KBYTES);
    const short* vb = (const short*)(smem + 2 * KBYTES + cur * VBYTES);

    // ---- swapped QK: T[key][q], A = K rows (this key-half), B = Q regs ----
    f32x16 s = Z16;
    __builtin_amdgcn_s_setprio(1);
    #pragma unroll
    for (int ch = 0; ch < 4; ++ch) {
      bf16x8 akf = *(const bf16x8*)&kb[(kho + c) * KSTR + ch * 16 + hi * 8];
      s = __builtin_amdgcn_mfma_f32_32x32x16_bf16(akf, aq[ch], s, 0, 0, 0);
    }
    __builtin_amdgcn_s_setprio(0);

    // ---- softmax numerator, no shift; reg g = key kv0+kho+(g&3)+8(g>>2)+4hi, q=q0w+c ----
    const int rel = kv0 + kho - q0w;
    if (rel >= -224 && rel <= 224) {   // whole 32q x 32k sub-tile inside band
      #pragma unroll
      for (int g = 0; g < 16; ++g) {
        const float p = exp2f(s[g]);
        s[g] = p; lsum += p;
      }
    } else {
      const int bm = rel + 4 * hi - c + WIN;
      #pragma unroll
      for (int g = 0; g < 16; ++g) {
        const int ro = (g & 3) + 8 * (g >> 2);
        const float p = ((unsigned)(bm + ro) <= 2u * WIN) ? exp2f(s[g]) : 0.f;
        s[g] = p; lsum += p;
      }
    }

    // ---- PV: A-frag slot j of chunk kt = s[kt*8+j]; B-frag = ONE b128 from permuted V ----
    __builtin_amdgcn_s_setprio(1);
    #pragma unroll
    for (int kt = 0; kt < 2; ++kt) {
      u32x4 pau;
      #pragma unroll
      for (int p2 = 0; p2 < 4; ++p2)
        pau[p2] = cvt2(s[kt * 8 + 2 * p2], s[kt * 8 + 2 * p2 + 1]);
      const bf16x8 pa = __builtin_bit_cast(bf16x8, pau);
      const int vo = kho + kt * 16 + hi * 8;   // permuted cols: keys {4hi+0..3, 8+4hi+0..3}
      bf16x8 bv0 = *(const bf16x8*)&vb[c * VSTR + vo];
      acc0 = __builtin_amdgcn_mfma_f32_32x32x16_bf16(pa, bv0, acc0, 0, 0, 0);
      bf16x8 bv1 = *(const bf16x8*)&vb[(32 + c) * VSTR + vo];
      acc1 = __builtin_amdgcn_mfma_f32_32x32x16_bf16(pa, bv1, acc1, 0, 0, 0);
    }
    __builtin_amdgcn_s_setprio(0);

    // ---- stage tile t+1 into the other buffer, prefetch t+2, single publish barrier ----
    if (t + 1 < nt) {
      STAGE_TO(cur ^ 1);
      if (t + 2 < nt) LOAD_TILE();
      __syncthreads();
    }
    cur ^= 1;
  }

  // ---- epilogue: merge key halves (pure adds, shared shift); overlay on dead K/V LDS ----
  lsum += __shfl_xor(lsum, 32);   // combine hi halves (same q=c column)
  __syncthreads();                // all tile reads done -> overlay is safe
  float* o_mrg = (float*)smem;                   // [4][32][64]
  float* l_par = (float*)(smem + LPAR_OFF);      // [2][4][32]
  if (hi == 0) l_par[(kh * 4 + qg) * 32 + c] = lsum;
  if (kh == 0) {
    #pragma unroll
    for (int g = 0; g < 16; ++g) {
      const int qrow = (g & 3) + 8 * (g >> 2) + 4 * hi;
      o_mrg[(qg * 32 + qrow) * HEAD_D + c]      = acc0[g];
      o_mrg[(qg * 32 + qrow) * HEAD_D + 32 + c] = acc1[g];
    }
  }
  __syncthreads();                // publish partials
  if (kh == 1) {
    if (hi == 0) l_par[qg * 32 + c] = 1.0f / (l_par[qg * 32 + c] + l_par[(4 + qg) * 32 + c]);
    __asm__ volatile("s_waitcnt lgkmcnt(0)" ::: "memory");   // same-wave write->read (rule #18)
    __builtin_amdgcn_sched_barrier(0);
    #pragma unroll
    for (int g = 0; g < 16; ++g) {
      const int qrow = (g & 3) + 8 * (g >> 2) + 4 * hi;
      const float iv = l_par[qg * 32 + qrow];    // lane-uniform -> LDS broadcast
      float* orow = Op + (size_t)(q0w + qrow) * HEAD_D;
      orow[c]      = (o_mrg[(qg * 32 + qrow) * HEAD_D + c]      + acc0[g]) * iv;
      orow[32 + c] = (o_mrg[(qg * 32 + qrow) * HEAD_D + 32 + c] + acc1[g]) * iv;
    }
  }
}

extern "C" void kernel_launch(void* const* d_in, const int* in_sizes, int n_in,
                              void* d_out, int out_size, void* d_ws, size_t ws_size,
                              hipStream_t stream) {
  const float* q = (const float*)d_in[0];
  const float* k = (const float*)d_in[1];
  const float* v = (const float*)d_in[2];
  float* o = (float*)d_out;
  const int blocks = 2 * 16 * (S_LEN / QBLK);  // 1024
  swa_fwd<<<dim3(blocks), dim3(512), 0, stream>>>(q, k, v, o);
}

// Round 8
// 52.200 us; speedup vs baseline: 6.7459x; 6.7459x over previous
//
#include <hip/hip_runtime.h>
#include <hip/hip_bf16.h>

typedef __attribute__((ext_vector_type(4)))  float f32x4;
typedef __attribute__((ext_vector_type(16))) float f32x16;
typedef __attribute__((ext_vector_type(8)))  short bf16x8;
typedef __attribute__((ext_vector_type(4)))  unsigned u32x4;

#define S_LEN 4096
#define HEAD_D 64
#define WIN 256
#define QBLK 128
#define KVBLK 64
#define KSTR 72   // k_lds row stride (shorts): b128 reads hit the 8-round LDS minimum
#define VSTR 72   // vt_lds row stride (shorts), [d][key'] with key' = key bits2<->3 swapped
#define QSCALE 0.18033688f   // log2(e)/8 folded into Q; no numerator shift (scores |s|<~10)

#define KBYTES (KVBLK * KSTR * 2)    // 9216 B per K buffer
#define VBYTES (HEAD_D * VSTR * 2)   // 9216 B per V buffer
// layout: k0@0, k1@KBYTES, vt0@2K, vt1@2K+V | epilogue overlay o_mrg[4][32][64] f32 @0
#define LPAR_OFF (2 * KBYTES + 2 * VBYTES)          // 36864
#define SMEM_BYTES (LPAR_OFF + 2 * 4 * 32 * 4)      // +1KB l partials = 37888

// HW packed f32->bf16 (RNE), 1 instr for 2 values
static __device__ __forceinline__ unsigned cvt2(float lo, float hi) {
  unsigned r;
  asm("v_cvt_pk_bf16_f32 %0, %1, %2" : "=v"(r) : "v"(lo), "v"(hi));
  return r;
}

__global__ __launch_bounds__(512, 4)   // R7's (512,8) forced VGPR=32 -> 1.6GB scratch spill
void swa_fwd(const float* __restrict__ Q, const float* __restrict__ K,
             const float* __restrict__ V, float* __restrict__ O) {
  __shared__ __attribute__((aligned(16))) char smem[SMEM_BYTES];

  const int tid  = threadIdx.x;
  const int widx = tid >> 6;
  const int lane = tid & 63;
  const int hi   = lane >> 5;
  const int c    = lane & 31;
  const int qg   = widx & 3;    // q-group: 32 rows
  const int kh   = widx >> 2;   // key half of each 64-key tile
  const int kho  = kh * 32;

  // XCD swizzle: 4 contiguous bh per XCD, qb fastest -> neighbor-qb L2 reuse.
  const int pb  = blockIdx.x;
  const int bh  = (pb & 7) * 4 + ((pb >> 3) >> 5);
  const int qb  = (pb >> 3) & 31;
  const int bq0 = qb * QBLK;
  const int q0w = bq0 + qg * 32;

  const size_t base = (size_t)bh * S_LEN * HEAD_D;
  const float* Qp = Q + base;
  const float* Kp = K + base;
  const float* Vp = V + base;
  float*       Op = O + base;

  const f32x16 Z16 = {0.f,0.f,0.f,0.f,0.f,0.f,0.f,0.f,0.f,0.f,0.f,0.f,0.f,0.f,0.f,0.f};

  // ---- Q B-fragments: lane holds Q[q0w+c][ch*16 + hi*8 + j]*QSCALE ----
  bf16x8 aq[4];
  {
    const float* qr = Qp + (size_t)(q0w + c) * HEAD_D + hi * 8;
    #pragma unroll
    for (int ch = 0; ch < 4; ++ch) {
      f32x4 x0 = *(const f32x4*)(qr + ch * 16);
      f32x4 x1 = *(const f32x4*)(qr + ch * 16 + 4);
      u32x4 au;
      au[0] = cvt2(x0[0] * QSCALE, x0[1] * QSCALE);
      au[1] = cvt2(x0[2] * QSCALE, x0[3] * QSCALE);
      au[2] = cvt2(x1[0] * QSCALE, x1[1] * QSCALE);
      au[3] = cvt2(x1[2] * QSCALE, x1[3] * QSCALE);
      aq[ch] = __builtin_bit_cast(bf16x8, au);
    }
  }

  f32x16 acc0 = Z16, acc1 = Z16;   // O-partial [32q x d0-31 / d32-63] for this key-half
  float lsum = 0.f;

  const int lo   = max(0, bq0 - WIN);
  const int khiB = min(S_LEN, bq0 + QBLK + WIN);
  const int nt   = (khiB - lo) >> 6;   // >= 6; multiples of 64; keys always in [0,S)

  // staging: K coalesced rows (8 lanes/row, b128 LDS write);
  // V: thread owns key pair (key2,key2+1) x 4 d, packs 2 keys/one b32 write at permuted col
  const int krow  = tid >> 3;          // 0..63
  const int kc8   = (tid & 7) << 3;    // 0..56
  const int key2  = (tid & 31) << 1;   // 0..62 (even)
  const int key2p = (key2 & ~12) | ((key2 & 4) << 1) | ((key2 & 8) >> 1);  // bits 2<->3
  const int vd4   = (tid >> 5) << 2;   // 0..60
  const float* kpt  = Kp + (size_t)(lo + krow) * HEAD_D + kc8;
  const float* vpt0 = Vp + (size_t)(lo + key2) * HEAD_D + vd4;
  const float* vpt1 = vpt0 + HEAD_D;

  f32x4 ka0, ka1, va0, va1;
  #define LOAD_TILE() do {                         \
    ka0 = *(const f32x4*)kpt;                      \
    ka1 = *(const f32x4*)(kpt + 4);                \
    va0 = *(const f32x4*)vpt0;                     \
    va1 = *(const f32x4*)vpt1;                     \
    kpt  += KVBLK * HEAD_D;                        \
    vpt0 += KVBLK * HEAD_D;                        \
    vpt1 += KVBLK * HEAD_D;                        \
  } while (0)

  #define STAGE_TO(buf) do {                                              \
    short* kb_ = (short*)(smem + (buf) * KBYTES);                         \
    short* vb_ = (short*)(smem + 2 * KBYTES + (buf) * VBYTES);            \
    u32x4 kw;                                                             \
    kw[0] = cvt2(ka0[0], ka0[1]);                                         \
    kw[1] = cvt2(ka0[2], ka0[3]);                                         \
    kw[2] = cvt2(ka1[0], ka1[1]);                                         \
    kw[3] = cvt2(ka1[2], ka1[3]);                                         \
    *(u32x4*)&kb_[krow * KSTR + kc8] = kw;                                \
    _Pragma("unroll")                                                     \
    for (int j = 0; j < 4; ++j)                                           \
      *(unsigned*)&vb_[(vd4 + j) * VSTR + key2p] = cvt2(va0[j], va1[j]);  \
  } while (0)

  // prologue: stage tile 0, prefetch tile 1
  LOAD_TILE();
  STAGE_TO(0);
  LOAD_TILE();
  __syncthreads();

  int cur = 0;
  for (int t = 0; t < nt; ++t) {
    const int kv0 = lo + (t << 6);
    const short* kb = (const short*)(smem + cur * KBYTES);
    const short* vb = (const short*)(smem + 2 * KBYTES + cur * VBYTES);

    // ---- swapped QK: T[key][q], A = K rows (this key-half), B = Q regs ----
    f32x16 s = Z16;
    __builtin_amdgcn_s_setprio(1);
    #pragma unroll
    for (int ch = 0; ch < 4; ++ch) {
      bf16x8 akf = *(const bf16x8*)&kb[(kho + c) * KSTR + ch * 16 + hi * 8];
      s = __builtin_amdgcn_mfma_f32_32x32x16_bf16(akf, aq[ch], s, 0, 0, 0);
    }
    __builtin_amdgcn_s_setprio(0);

    // ---- softmax numerator, no shift; reg g = key kv0+kho+(g&3)+8(g>>2)+4hi, q=q0w+c ----
    const int rel = kv0 + kho - q0w;
    if (rel >= -224 && rel <= 224) {   // whole 32q x 32k sub-tile inside band
      #pragma unroll
      for (int g = 0; g < 16; ++g) {
        const float p = exp2f(s[g]);
        s[g] = p; lsum += p;
      }
    } else {
      const int bm = rel + 4 * hi - c + WIN;
      #pragma unroll
      for (int g = 0; g < 16; ++g) {
        const int ro = (g & 3) + 8 * (g >> 2);
        const float p = ((unsigned)(bm + ro) <= 2u * WIN) ? exp2f(s[g]) : 0.f;
        s[g] = p; lsum += p;
      }
    }

    // ---- PV: A-frag slot j of chunk kt = s[kt*8+j]; B-frag = ONE b128 from permuted V ----
    __builtin_amdgcn_s_setprio(1);
    #pragma unroll
    for (int kt = 0; kt < 2; ++kt) {
      u32x4 pau;
      #pragma unroll
      for (int p2 = 0; p2 < 4; ++p2)
        pau[p2] = cvt2(s[kt * 8 + 2 * p2], s[kt * 8 + 2 * p2 + 1]);
      const bf16x8 pa = __builtin_bit_cast(bf16x8, pau);
      const int vo = kho + kt * 16 + hi * 8;   // permuted cols: keys {4hi+0..3, 8+4hi+0..3}
      bf16x8 bv0 = *(const bf16x8*)&vb[c * VSTR + vo];
      acc0 = __builtin_amdgcn_mfma_f32_32x32x16_bf16(pa, bv0, acc0, 0, 0, 0);
      bf16x8 bv1 = *(const bf16x8*)&vb[(32 + c) * VSTR + vo];
      acc1 = __builtin_amdgcn_mfma_f32_32x32x16_bf16(pa, bv1, acc1, 0, 0, 0);
    }
    __builtin_amdgcn_s_setprio(0);

    // ---- stage tile t+1 into the other buffer, prefetch t+2, single publish barrier ----
    if (t + 1 < nt) {
      STAGE_TO(cur ^ 1);
      if (t + 2 < nt) LOAD_TILE();
      __syncthreads();
    }
    cur ^= 1;
  }

  // ---- epilogue: merge key halves (pure adds, shared shift); overlay on dead K/V LDS ----
  lsum += __shfl_xor(lsum, 32);   // combine hi halves (same q=c column)
  __syncthreads();                // all tile reads done -> overlay is safe
  float* o_mrg = (float*)smem;                   // [4][32][64]
  float* l_par = (float*)(smem + LPAR_OFF);      // [2][4][32]
  if (hi == 0) l_par[(kh * 4 + qg) * 32 + c] = lsum;
  if (kh == 0) {
    #pragma unroll
    for (int g = 0; g < 16; ++g) {
      const int qrow = (g & 3) + 8 * (g >> 2) + 4 * hi;
      o_mrg[(qg * 32 + qrow) * HEAD_D + c]      = acc0[g];
      o_mrg[(qg * 32 + qrow) * HEAD_D + 32 + c] = acc1[g];
    }
  }
  __syncthreads();                // publish partials
  if (kh == 1) {
    if (hi == 0) l_par[qg * 32 + c] = 1.0f / (l_par[qg * 32 + c] + l_par[(4 + qg) * 32 + c]);
    __asm__ volatile("s_waitcnt lgkmcnt(0)" ::: "memory");   // same-wave write->read (rule #18)
    __builtin_amdgcn_sched_barrier(0);
    #pragma unroll
    for (int g = 0; g < 16; ++g) {
      const int qrow = (g & 3) + 8 * (g >> 2) + 4 * hi;
      const float iv = l_par[qg * 32 + qrow];    // lane-uniform -> LDS broadcast
      float* orow = Op + (size_t)(q0w + qrow) * HEAD_D;
      orow[c]      = (o_mrg[(qg * 32 + qrow) * HEAD_D + c]      + acc0[g]) * iv;
      orow[32 + c] = (o_mrg[(qg * 32 + qrow) * HEAD_D + 32 + c] + acc1[g]) * iv;
    }
  }
}

extern "C" void kernel_launch(void* const* d_in, const int* in_sizes, int n_in,
                              void* d_out, int out_size, void* d_ws, size_t ws_size,
                              hipStream_t stream) {
  const float* q = (const float*)d_in[0];
  const float* k = (const float*)d_in[1];
  const float* v = (const float*)d_in[2];
  float* o = (float*)d_out;
  const int blocks = 2 * 16 * (S_LEN / QBLK);  // 1024
  swa_fwd<<<dim3(blocks), dim3(512), 0, stream>>>(q, k, v, o);
}

// Round 9
// 51.442 us; speedup vs baseline: 6.8452x; 1.0147x over previous
//
#include <hip/hip_runtime.h>
#include <hip/hip_bf16.h>

typedef __attribute__((ext_vector_type(4)))  float f32x4;
typedef __attribute__((ext_vector_type(16))) float f32x16;
typedef __attribute__((ext_vector_type(8)))  short bf16x8;
typedef __attribute__((ext_vector_type(4)))  unsigned u32x4;

#define S_LEN 4096
#define HEAD_D 64
#define WIN 256
#define QBLK 128
#define KVBLK 64
#define KSTR 72   // k_lds row stride (shorts)
#define VSTR 72   // vt_lds row stride (shorts), [d][key'] key' = key with bits2<->3 swapped
#define QSCALE 0.18033688f   // log2(e)/8 folded into Q; no numerator shift

#define KBYTES (KVBLK * KSTR * 2)    // 9216 B per K buffer
#define VBYTES (HEAD_D * VSTR * 2)   // 9216 B per V buffer
#define KHALF  (KBYTES / 2)          // buffer stride in shorts (4608)
#define VHALF  (VBYTES / 2)
#define LPAR_OFF (2 * KBYTES + 2 * VBYTES)          // 36864
#define SMEM_BYTES (LPAR_OFF + 2 * 4 * 32 * 4)      // 37888

static __device__ __forceinline__ unsigned cvt2(float lo, float hi) {
  unsigned r;
  asm("v_cvt_pk_bf16_f32 %0, %1, %2" : "=v"(r) : "v"(lo), "v"(hi));
  return r;
}

__global__ __launch_bounds__(512, 4)
void swa_fwd(const float* __restrict__ Q, const float* __restrict__ K,
             const float* __restrict__ V, float* __restrict__ O) {
  __shared__ __attribute__((aligned(16))) char smem[SMEM_BYTES];

  const int tid  = threadIdx.x;
  const int widx = tid >> 6;
  const int lane = tid & 63;
  const int hi   = lane >> 5;
  const int c    = lane & 31;
  const int qg   = widx & 3;
  const int kh   = widx >> 2;
  const int kho  = kh * 32;

  // XCD swizzle: 4 contiguous bh per XCD, qb fastest.
  const int pb  = blockIdx.x;
  const int bh  = (pb & 7) * 4 + ((pb >> 3) >> 5);
  const int qb  = (pb >> 3) & 31;
  const int bq0 = qb * QBLK;
  const int q0w = bq0 + qg * 32;

  const size_t base = (size_t)bh * S_LEN * HEAD_D;
  const float* Qp = Q + base;
  const float* Kp = K + base;
  const float* Vp = V + base;
  float*       Op = O + base;

  const f32x16 Z16 = {0.f,0.f,0.f,0.f,0.f,0.f,0.f,0.f,0.f,0.f,0.f,0.f,0.f,0.f,0.f,0.f};

  // ---- Q B-fragments ----
  bf16x8 aq[4];
  {
    const float* qr = Qp + (size_t)(q0w + c) * HEAD_D + hi * 8;
    #pragma unroll
    for (int ch = 0; ch < 4; ++ch) {
      f32x4 x0 = *(const f32x4*)(qr + ch * 16);
      f32x4 x1 = *(const f32x4*)(qr + ch * 16 + 4);
      u32x4 au;
      au[0] = cvt2(x0[0] * QSCALE, x0[1] * QSCALE);
      au[1] = cvt2(x0[2] * QSCALE, x0[3] * QSCALE);
      au[2] = cvt2(x1[0] * QSCALE, x1[1] * QSCALE);
      au[3] = cvt2(x1[2] * QSCALE, x1[3] * QSCALE);
      aq[ch] = __builtin_bit_cast(bf16x8, au);
    }
  }

  f32x16 acc0 = Z16, acc1 = Z16;
  float lsA = 0.f, lsB = 0.f;   // split denominator accumulators (shorter dep chain)

  const int lo   = max(0, bq0 - WIN);
  const int khiB = min(S_LEN, bq0 + QBLK + WIN);
  const int nt   = (khiB - lo) >> 6;   // in {6,8,10}: ALWAYS EVEN -> clean 2-unroll

  // staging lane assignment
  const int krow  = tid >> 3;
  const int kc8   = (tid & 7) << 3;
  const int key2  = (tid & 31) << 1;
  const int key2p = (key2 & ~12) | ((key2 & 4) << 1) | ((key2 & 8) >> 1);
  const int vd4   = (tid >> 5) << 2;

  // ---- hoisted LDS bases (all per-tile variation becomes ds imm offsets) ----
  short* const ksh = (short*)smem;
  short* const vsh = (short*)(smem + 2 * KBYTES);
  const short* const krd = ksh + (kho + c) * KSTR + hi * 8;     // QK reads
  const short* const vrd = vsh + c * VSTR + kho + hi * 8;       // PV reads
  short* const kwr = ksh + krow * KSTR + kc8;                   // K stage write
  short* const vwr = vsh + vd4 * VSTR + key2p;                  // V stage writes

  // ---- global offsets (32-bit, saddr form), one bump each per tile ----
  unsigned koff = (unsigned)(lo + krow) * HEAD_D + kc8;
  unsigned voff = (unsigned)(lo + key2) * HEAD_D + vd4;

  f32x4 ka0, ka1, va0, va1;
  #define LOAD_TILE() do {                          \
    ka0 = *(const f32x4*)(Kp + koff);               \
    ka1 = *(const f32x4*)(Kp + koff + 4);           \
    va0 = *(const f32x4*)(Vp + voff);               \
    va1 = *(const f32x4*)(Vp + voff + HEAD_D);      \
    koff += KVBLK * HEAD_D;                         \
    voff += KVBLK * HEAD_D;                         \
  } while (0)

  #define STAGE_TO(BUF) do {                                        \
    u32x4 kw;                                                       \
    kw[0] = cvt2(ka0[0], ka0[1]);                                   \
    kw[1] = cvt2(ka0[2], ka0[3]);                                   \
    kw[2] = cvt2(ka1[0], ka1[1]);                                   \
    kw[3] = cvt2(ka1[2], ka1[3]);                                   \
    *(u32x4*)&kwr[(BUF) * KHALF] = kw;                              \
    _Pragma("unroll")                                               \
    for (int j = 0; j < 4; ++j)                                     \
      *(unsigned*)&vwr[(BUF) * VHALF + j * VSTR] = cvt2(va0[j], va1[j]); \
  } while (0)

  #define TILE_BODY(T, BUF) do {                                              \
    const int kv0_ = lo + ((T) << 6);                                         \
    f32x16 s = Z16;                                                           \
    __builtin_amdgcn_s_setprio(1);                                            \
    _Pragma("unroll")                                                         \
    for (int ch = 0; ch < 4; ++ch) {                                          \
      bf16x8 akf = *(const bf16x8*)&krd[(BUF) * KHALF + ch * 16];             \
      s = __builtin_amdgcn_mfma_f32_32x32x16_bf16(akf, aq[ch], s, 0, 0, 0);   \
    }                                                                         \
    __builtin_amdgcn_s_setprio(0);                                            \
    const int rel_ = kv0_ + kho - q0w;                                        \
    if (rel_ >= -224 && rel_ <= 224) {                                        \
      _Pragma("unroll")                                                       \
      for (int g = 0; g < 16; g += 2) {                                       \
        const float p0 = exp2f(s[g]);                                         \
        const float p1 = exp2f(s[g + 1]);                                     \
        s[g] = p0; s[g + 1] = p1; lsA += p0; lsB += p1;                       \
      }                                                                       \
    } else {                                                                  \
      const int bm_ = rel_ + 4 * hi - c + WIN;                                \
      _Pragma("unroll")                                                       \
      for (int g = 0; g < 16; ++g) {                                          \
        const int ro_ = (g & 3) + 8 * (g >> 2);                               \
        const float p = ((unsigned)(bm_ + ro_) <= 2u * WIN) ? exp2f(s[g]) : 0.f; \
        s[g] = p; if (g & 1) lsB += p; else lsA += p;                         \
      }                                                                       \
    }                                                                         \
    __builtin_amdgcn_s_setprio(1);                                            \
    _Pragma("unroll")                                                         \
    for (int kt = 0; kt < 2; ++kt) {                                          \
      u32x4 pau;                                                              \
      _Pragma("unroll")                                                       \
      for (int p2 = 0; p2 < 4; ++p2)                                          \
        pau[p2] = cvt2(s[kt * 8 + 2 * p2], s[kt * 8 + 2 * p2 + 1]);           \
      const bf16x8 pa = __builtin_bit_cast(bf16x8, pau);                      \
      bf16x8 bv0 = *(const bf16x8*)&vrd[(BUF) * VHALF + kt * 16];             \
      acc0 = __builtin_amdgcn_mfma_f32_32x32x16_bf16(pa, bv0, acc0, 0, 0, 0); \
      bf16x8 bv1 = *(const bf16x8*)&vrd[(BUF) * VHALF + kt * 16 + 32 * VSTR]; \
      acc1 = __builtin_amdgcn_mfma_f32_32x32x16_bf16(pa, bv1, acc1, 0, 0, 0); \
    }                                                                         \
    __builtin_amdgcn_s_setprio(0);                                            \
    if ((T) + 1 < nt) {                                                       \
      STAGE_TO((BUF) ^ 1);                                                    \
      if ((T) + 2 < nt) LOAD_TILE();                                          \
      __syncthreads();                                                        \
    }                                                                         \
  } while (0)

  // prologue: stage tile 0 into buf 0, prefetch tile 1
  LOAD_TILE();
  STAGE_TO(0);
  LOAD_TILE();
  __syncthreads();

  for (int t = 0; t < nt; t += 2) {   // nt even: buffer index is compile-time
    TILE_BODY(t, 0);
    TILE_BODY(t + 1, 1);
  }

  // ---- epilogue: merge key halves; overlay on dead K/V LDS ----
  float lsum = lsA + lsB;
  lsum += __shfl_xor(lsum, 32);
  __syncthreads();
  float* o_mrg = (float*)smem;                   // [4][32][64]
  float* l_par = (float*)(smem + LPAR_OFF);      // [2][4][32]
  if (hi == 0) l_par[(kh * 4 + qg) * 32 + c] = lsum;
  if (kh == 0) {
    #pragma unroll
    for (int g = 0; g < 16; ++g) {
      const int qrow = (g & 3) + 8 * (g >> 2) + 4 * hi;
      o_mrg[(qg * 32 + qrow) * HEAD_D + c]      = acc0[g];
      o_mrg[(qg * 32 + qrow) * HEAD_D + 32 + c] = acc1[g];
    }
  }
  __syncthreads();
  if (kh == 1) {
    if (hi == 0) l_par[qg * 32 + c] = 1.0f / (l_par[qg * 32 + c] + l_par[(4 + qg) * 32 + c]);
    __asm__ volatile("s_waitcnt lgkmcnt(0)" ::: "memory");
    __builtin_amdgcn_sched_barrier(0);
    #pragma unroll
    for (int g = 0; g < 16; ++g) {
      const int qrow = (g & 3) + 8 * (g >> 2) + 4 * hi;
      const float iv = l_par[qg * 32 + qrow];
      float* orow = Op + (size_t)(q0w + qrow) * HEAD_D;
      orow[c]      = (o_mrg[(qg * 32 + qrow) * HEAD_D + c]      + acc0[g]) * iv;
      orow[32 + c] = (o_mrg[(qg * 32 + qrow) * HEAD_D + 32 + c] + acc1[g]) * iv;
    }
  }
}

extern "C" void kernel_launch(void* const* d_in, const int* in_sizes, int n_in,
                              void* d_out, int out_size, void* d_ws, size_t ws_size,
                              hipStream_t stream) {
  const float* q = (const float*)d_in[0];
  const float* k = (const float*)d_in[1];
  const float* v = (const float*)d_in[2];
  float* o = (float*)d_out;
  const int blocks = 2 * 16 * (S_LEN / QBLK);  // 1024
  swa_fwd<<<dim3(blocks), dim3(512), 0, stream>>>(q, k, v, o);
}

// Round 10
// 51.254 us; speedup vs baseline: 6.8704x; 1.0037x over previous
//
#include <hip/hip_runtime.h>
#include <hip/hip_bf16.h>

typedef __attribute__((ext_vector_type(4)))  float f32x4;
typedef __attribute__((ext_vector_type(16))) float f32x16;
typedef __attribute__((ext_vector_type(8)))  short bf16x8;
typedef __attribute__((ext_vector_type(4)))  unsigned u32x4;

#define S_LEN 4096
#define HEAD_D 64
#define WIN 256
#define QBLK 128
#define KVBLK 64
#define KSTR 72   // k_lds row stride (shorts)
#define VSTR 72   // vt_lds row stride (shorts), [d][key'] key' = key with bits2<->3 swapped
#define QSCALE 0.18033688f   // log2(e)/8 folded into Q; no numerator shift

#define KBYTES (KVBLK * KSTR * 2)    // 9216 B per K buffer
#define VBYTES (HEAD_D * VSTR * 2)   // 9216 B per V buffer
#define KHALF  (KBYTES / 2)          // buffer stride in shorts (4608)
#define VHALF  (VBYTES / 2)
#define LPAR_OFF (2 * KBYTES + 2 * VBYTES)          // 36864
#define SMEM_BYTES (LPAR_OFF + 2 * 4 * 32 * 4)      // 37888

static __device__ __forceinline__ unsigned cvt2(float lo, float hi) {
  unsigned r;
  asm("v_cvt_pk_bf16_f32 %0, %1, %2" : "=v"(r) : "v"(lo), "v"(hi));
  return r;
}

// Publish barrier that does NOT drain vmcnt: in-flight global prefetch loads
// (register destinations only) ride across; LDS ordering guaranteed by lgkmcnt(0).
// __syncthreads would emit s_waitcnt vmcnt(0) and expose prefetch latency every tile.
#define PUB_BARRIER() do {                              \
    __builtin_amdgcn_sched_barrier(0);                  \
    asm volatile("s_waitcnt lgkmcnt(0)" ::: "memory");  \
    __builtin_amdgcn_s_barrier();                       \
    __builtin_amdgcn_sched_barrier(0);                  \
  } while (0)

__global__ __launch_bounds__(512, 4)
void swa_fwd(const float* __restrict__ Q, const float* __restrict__ K,
             const float* __restrict__ V, float* __restrict__ O) {
  __shared__ __attribute__((aligned(16))) char smem[SMEM_BYTES];

  const int tid  = threadIdx.x;
  const int widx = tid >> 6;
  const int lane = tid & 63;
  const int hi   = lane >> 5;
  const int c    = lane & 31;
  const int qg   = widx & 3;
  const int kh   = widx >> 2;
  const int kho  = kh * 32;

  // XCD swizzle: 4 contiguous bh per XCD, qb fastest.
  const int pb  = blockIdx.x;
  const int bh  = (pb & 7) * 4 + ((pb >> 3) >> 5);
  const int qb  = (pb >> 3) & 31;
  const int bq0 = qb * QBLK;
  const int q0w = bq0 + qg * 32;

  const size_t base = (size_t)bh * S_LEN * HEAD_D;
  const float* Qp = Q + base;
  const float* Kp = K + base;
  const float* Vp = V + base;
  float*       Op = O + base;

  const f32x16 Z16 = {0.f,0.f,0.f,0.f,0.f,0.f,0.f,0.f,0.f,0.f,0.f,0.f,0.f,0.f,0.f,0.f};

  // ---- Q B-fragments ----
  bf16x8 aq[4];
  {
    const float* qr = Qp + (size_t)(q0w + c) * HEAD_D + hi * 8;
    #pragma unroll
    for (int ch = 0; ch < 4; ++ch) {
      f32x4 x0 = *(const f32x4*)(qr + ch * 16);
      f32x4 x1 = *(const f32x4*)(qr + ch * 16 + 4);
      u32x4 au;
      au[0] = cvt2(x0[0] * QSCALE, x0[1] * QSCALE);
      au[1] = cvt2(x0[2] * QSCALE, x0[3] * QSCALE);
      au[2] = cvt2(x1[0] * QSCALE, x1[1] * QSCALE);
      au[3] = cvt2(x1[2] * QSCALE, x1[3] * QSCALE);
      aq[ch] = __builtin_bit_cast(bf16x8, au);
    }
  }

  f32x16 acc0 = Z16, acc1 = Z16;
  float lsA = 0.f, lsB = 0.f;

  const int lo   = max(0, bq0 - WIN);
  const int khiB = min(S_LEN, bq0 + QBLK + WIN);
  const int nt   = (khiB - lo) >> 6;   // in {6,8,10}: always even -> clean 2-unroll

  // staging lane assignment
  const int krow  = tid >> 3;
  const int kc8   = (tid & 7) << 3;
  const int key2  = (tid & 31) << 1;
  const int key2p = (key2 & ~12) | ((key2 & 4) << 1) | ((key2 & 8) >> 1);
  const int vd4   = (tid >> 5) << 2;

  // ---- hoisted LDS bases ----
  short* const ksh = (short*)smem;
  short* const vsh = (short*)(smem + 2 * KBYTES);
  const short* const krd = ksh + (kho + c) * KSTR + hi * 8;     // QK reads
  const short* const vrd = vsh + c * VSTR + kho + hi * 8;       // PV reads
  short* const kwr = ksh + krow * KSTR + kc8;                   // K stage write
  short* const vwr = vsh + vd4 * VSTR + key2p;                  // V stage writes

  // ---- global offsets (32-bit), one bump each per tile ----
  unsigned koff = (unsigned)(lo + krow) * HEAD_D + kc8;
  unsigned voff = (unsigned)(lo + key2) * HEAD_D + vd4;

  f32x4 ka0, ka1, va0, va1;
  #define LOAD_TILE() do {                          \
    ka0 = *(const f32x4*)(Kp + koff);               \
    ka1 = *(const f32x4*)(Kp + koff + 4);           \
    va0 = *(const f32x4*)(Vp + voff);               \
    va1 = *(const f32x4*)(Vp + voff + HEAD_D);      \
    koff += KVBLK * HEAD_D;                         \
    voff += KVBLK * HEAD_D;                         \
  } while (0)

  #define STAGE_TO(BUF) do {                                        \
    u32x4 kw;                                                       \
    kw[0] = cvt2(ka0[0], ka0[1]);                                   \
    kw[1] = cvt2(ka0[2], ka0[3]);                                   \
    kw[2] = cvt2(ka1[0], ka1[1]);                                   \
    kw[3] = cvt2(ka1[2], ka1[3]);                                   \
    *(u32x4*)&kwr[(BUF) * KHALF] = kw;                              \
    _Pragma("unroll")                                               \
    for (int j = 0; j < 4; ++j)                                     \
      *(unsigned*)&vwr[(BUF) * VHALF + j * VSTR] = cvt2(va0[j], va1[j]); \
  } while (0)

  #define TILE_BODY(T, BUF) do {                                              \
    const int kv0_ = lo + ((T) << 6);                                         \
    f32x16 s = Z16;                                                           \
    __builtin_amdgcn_s_setprio(1);                                            \
    _Pragma("unroll")                                                         \
    for (int ch = 0; ch < 4; ++ch) {                                          \
      bf16x8 akf = *(const bf16x8*)&krd[(BUF) * KHALF + ch * 16];             \
      s = __builtin_amdgcn_mfma_f32_32x32x16_bf16(akf, aq[ch], s, 0, 0, 0);   \
    }                                                                         \
    __builtin_amdgcn_s_setprio(0);                                            \
    const int rel_ = kv0_ + kho - q0w;                                        \
    if (rel_ >= -224 && rel_ <= 224) {                                        \
      _Pragma("unroll")                                                       \
      for (int g = 0; g < 16; g += 2) {                                       \
        const float p0 = exp2f(s[g]);                                         \
        const float p1 = exp2f(s[g + 1]);                                     \
        s[g] = p0; s[g + 1] = p1; lsA += p0; lsB += p1;                       \
      }                                                                       \
    } else {                                                                  \
      const int bm_ = rel_ + 4 * hi - c + WIN;                                \
      _Pragma("unroll")                                                       \
      for (int g = 0; g < 16; ++g) {                                          \
        const int ro_ = (g & 3) + 8 * (g >> 2);                               \
        const float p = ((unsigned)(bm_ + ro_) <= 2u * WIN) ? exp2f(s[g]) : 0.f; \
        s[g] = p; if (g & 1) lsB += p; else lsA += p;                         \
      }                                                                       \
    }                                                                         \
    __builtin_amdgcn_s_setprio(1);                                            \
    _Pragma("unroll")                                                         \
    for (int kt = 0; kt < 2; ++kt) {                                          \
      u32x4 pau;                                                              \
      _Pragma("unroll")                                                       \
      for (int p2 = 0; p2 < 4; ++p2)                                          \
        pau[p2] = cvt2(s[kt * 8 + 2 * p2], s[kt * 8 + 2 * p2 + 1]);           \
      const bf16x8 pa = __builtin_bit_cast(bf16x8, pau);                      \
      bf16x8 bv0 = *(const bf16x8*)&vrd[(BUF) * VHALF + kt * 16];             \
      acc0 = __builtin_amdgcn_mfma_f32_32x32x16_bf16(pa, bv0, acc0, 0, 0, 0); \
      bf16x8 bv1 = *(const bf16x8*)&vrd[(BUF) * VHALF + kt * 16 + 32 * VSTR]; \
      acc1 = __builtin_amdgcn_mfma_f32_32x32x16_bf16(pa, bv1, acc1, 0, 0, 0); \
    }                                                                         \
    __builtin_amdgcn_s_setprio(0);                                            \
    if ((T) + 1 < nt) {                                                       \
      STAGE_TO((BUF) ^ 1);                                                    \
      if ((T) + 2 < nt) LOAD_TILE();                                          \
      PUB_BARRIER();                                                          \
    }                                                                         \
  } while (0)

  // prologue: stage tile 0 into buf 0, prefetch tile 1 (loads ride across barrier)
  LOAD_TILE();
  STAGE_TO(0);
  LOAD_TILE();
  PUB_BARRIER();

  for (int t = 0; t < nt; t += 2) {   // nt even: buffer index is compile-time
    TILE_BODY(t, 0);
    TILE_BODY(t + 1, 1);
  }

  // ---- epilogue: merge key halves; overlay on dead K/V LDS (full __syncthreads ok here) ----
  float lsum = lsA + lsB;
  lsum += __shfl_xor(lsum, 32);
  __syncthreads();
  float* o_mrg = (float*)smem;                   // [4][32][64]
  float* l_par = (float*)(smem + LPAR_OFF);      // [2][4][32]
  if (hi == 0) l_par[(kh * 4 + qg) * 32 + c] = lsum;
  if (kh == 0) {
    #pragma unroll
    for (int g = 0; g < 16; ++g) {
      const int qrow = (g & 3) + 8 * (g >> 2) + 4 * hi;
      o_mrg[(qg * 32 + qrow) * HEAD_D + c]      = acc0[g];
      o_mrg[(qg * 32 + qrow) * HEAD_D + 32 + c] = acc1[g];
    }
  }
  __syncthreads();
  if (kh == 1) {
    if (hi == 0) l_par[qg * 32 + c] = 1.0f / (l_par[qg * 32 + c] + l_par[(4 + qg) * 32 + c]);
    __asm__ volatile("s_waitcnt lgkmcnt(0)" ::: "memory");
    __builtin_amdgcn_sched_barrier(0);
    #pragma unroll
    for (int g = 0; g < 16; ++g) {
      const int qrow = (g & 3) + 8 * (g >> 2) + 4 * hi;
      const float iv = l_par[qg * 32 + qrow];
      float* orow = Op + (size_t)(q0w + qrow) * HEAD_D;
      orow[c]      = (o_mrg[(qg * 32 + qrow) * HEAD_D + c]      + acc0[g]) * iv;
      orow[32 + c] = (o_mrg[(qg * 32 + qrow) * HEAD_D + 32 + c] + acc1[g]) * iv;
    }
  }
}

extern "C" void kernel_launch(void* const* d_in, const int* in_sizes, int n_in,
                              void* d_out, int out_size, void* d_ws, size_t ws_size,
                              hipStream_t stream) {
  const float* q = (const float*)d_in[0];
  const float* k = (const float*)d_in[1];
  const float* v = (const float*)d_in[2];
  float* o = (float*)d_out;
  const int blocks = 2 * 16 * (S_LEN / QBLK);  // 1024
  swa_fwd<<<dim3(blocks), dim3(512), 0, stream>>>(q, k, v, o);
}

// Round 11
// 47.223 us; speedup vs baseline: 7.4567x; 1.0853x over previous
//
#include <hip/hip_runtime.h>
#include <hip/hip_bf16.h>

typedef __attribute__((ext_vector_type(4)))  float f32x4;
typedef __attribute__((ext_vector_type(16))) float f32x16;
typedef __attribute__((ext_vector_type(8)))  short bf16x8;
typedef __attribute__((ext_vector_type(4)))  unsigned u32x4;

#define S_LEN 4096
#define HEAD_D 64
#define WIN 256
#define QBLK 128
#define KVBLK 64
#define KSTR 72   // k_lds row stride (shorts)
#define VSTR 72   // vt_lds row stride (shorts), [d][key'] key' = key with bits2<->3 swapped
#define QSCALE 0.18033688f   // log2(e)/8 folded into Q; no numerator shift

#define KBYTES (KVBLK * KSTR * 2)    // 9216 B per K buffer
#define VBYTES (HEAD_D * VSTR * 2)   // 9216 B per V buffer
#define KHALF  (KBYTES / 2)          // buffer stride in shorts (4608)
#define VHALF  (VBYTES / 2)
#define LPAR_OFF (2 * KBYTES + 2 * VBYTES)          // 36864
#define SMEM_BYTES (LPAR_OFF + 2 * 4 * 32 * 4)      // 37888

static __device__ __forceinline__ unsigned cvt2(float lo, float hi) {
  unsigned r;
  asm("v_cvt_pk_bf16_f32 %0, %1, %2" : "=v"(r) : "v"(lo), "v"(hi));
  return r;
}

// Publish barrier that does NOT drain vmcnt (in-flight prefetch loads ride across).
#define PUB_BARRIER() do {                              \
    __builtin_amdgcn_sched_barrier(0);                  \
    asm volatile("s_waitcnt lgkmcnt(0)" ::: "memory");  \
    __builtin_amdgcn_s_barrier();                       \
    __builtin_amdgcn_sched_barrier(0);                  \
  } while (0)

__global__ __launch_bounds__(512, 4)
void swa_fwd(const float* __restrict__ Q, const float* __restrict__ K,
             const float* __restrict__ V, float* __restrict__ O) {
  __shared__ __attribute__((aligned(16))) char smem[SMEM_BYTES];

  const int tid  = threadIdx.x;
  const int widx = tid >> 6;
  const int lane = tid & 63;
  const int hi   = lane >> 5;
  const int c    = lane & 31;
  const int qg   = widx & 3;
  const int kh   = widx >> 2;
  const int kho  = kh * 32;

  // XCD swizzle: 4 contiguous bh per XCD, qb fastest.
  const int pb  = blockIdx.x;
  const int bh  = (pb & 7) * 4 + ((pb >> 3) >> 5);
  const int qb  = (pb >> 3) & 31;
  const int bq0 = qb * QBLK;
  const int q0w = bq0 + qg * 32;

  const size_t base = (size_t)bh * S_LEN * HEAD_D;
  const float* Qp = Q + base;
  const float* Kp = K + base;
  const float* Vp = V + base;
  float*       Op = O + base;

  const f32x16 Z16 = {0.f,0.f,0.f,0.f,0.f,0.f,0.f,0.f,0.f,0.f,0.f,0.f,0.f,0.f,0.f,0.f};

  // ---- Q B-fragments ----
  bf16x8 aq[4];
  {
    const float* qr = Qp + (size_t)(q0w + c) * HEAD_D + hi * 8;
    #pragma unroll
    for (int ch = 0; ch < 4; ++ch) {
      f32x4 x0 = *(const f32x4*)(qr + ch * 16);
      f32x4 x1 = *(const f32x4*)(qr + ch * 16 + 4);
      u32x4 au;
      au[0] = cvt2(x0[0] * QSCALE, x0[1] * QSCALE);
      au[1] = cvt2(x0[2] * QSCALE, x0[3] * QSCALE);
      au[2] = cvt2(x1[0] * QSCALE, x1[1] * QSCALE);
      au[3] = cvt2(x1[2] * QSCALE, x1[3] * QSCALE);
      aq[ch] = __builtin_bit_cast(bf16x8, au);
    }
  }

  f32x16 acc0 = Z16, acc1 = Z16;
  float lsA = 0.f, lsB = 0.f;

  const int lo   = max(0, bq0 - WIN);
  const int khiB = min(S_LEN, bq0 + QBLK + WIN);
  const int nt   = (khiB - lo) >> 6;   // in {6,8,10}: always even -> clean 2-unroll

  // staging lane assignment
  const int krow  = tid >> 3;
  const int kc8   = (tid & 7) << 3;
  const int key2  = (tid & 31) << 1;
  const int key2p = (key2 & ~12) | ((key2 & 4) << 1) | ((key2 & 8) >> 1);
  const int vd4   = (tid >> 5) << 2;

  // ---- hoisted LDS bases ----
  short* const ksh = (short*)smem;
  short* const vsh = (short*)(smem + 2 * KBYTES);
  const short* const krd = ksh + (kho + c) * KSTR + hi * 8;     // QK reads
  const short* const vrd = vsh + c * VSTR + kho + hi * 8;       // PV reads
  short* const kwr = ksh + krow * KSTR + kc8;                   // K stage write
  short* const vwr = vsh + vd4 * VSTR + key2p;                  // V stage writes

  // ---- global offsets (32-bit), one bump each per tile ----
  unsigned koff = (unsigned)(lo + krow) * HEAD_D + kc8;
  unsigned voff = (unsigned)(lo + key2) * HEAD_D + vd4;

  f32x4 ka0, ka1, va0, va1;
  #define LOAD_TILE() do {                          \
    ka0 = *(const f32x4*)(Kp + koff);               \
    ka1 = *(const f32x4*)(Kp + koff + 4);           \
    va0 = *(const f32x4*)(Vp + voff);               \
    va1 = *(const f32x4*)(Vp + voff + HEAD_D);      \
    koff += KVBLK * HEAD_D;                         \
    voff += KVBLK * HEAD_D;                         \
  } while (0)

  #define STAGE_TO(BUF) do {                                        \
    u32x4 kw;                                                       \
    kw[0] = cvt2(ka0[0], ka0[1]);                                   \
    kw[1] = cvt2(ka0[2], ka0[3]);                                   \
    kw[2] = cvt2(ka1[0], ka1[1]);                                   \
    kw[3] = cvt2(ka1[2], ka1[3]);                                   \
    *(u32x4*)&kwr[(BUF) * KHALF] = kw;                              \
    _Pragma("unroll")                                               \
    for (int j = 0; j < 4; ++j)                                     \
      *(unsigned*)&vwr[(BUF) * VHALF + j * VSTR] = cvt2(va0[j], va1[j]); \
  } while (0)

  // Tile body, reordered for latency overlap:
  //   QK-issue -> STAGE(t+1, independent of s) -> LOAD(t+2) -> SM -> PV -> barrier
  // STAGE fills the QK MFMA-chain latency window; LOAD gets a full tile of slack.
  #define TILE_BODY(T, BUF) do {                                              \
    const int kv0_ = lo + ((T) << 6);                                         \
    f32x16 s = Z16;                                                           \
    __builtin_amdgcn_s_setprio(1);                                            \
    _Pragma("unroll")                                                         \
    for (int ch = 0; ch < 4; ++ch) {                                          \
      bf16x8 akf = *(const bf16x8*)&krd[(BUF) * KHALF + ch * 16];             \
      s = __builtin_amdgcn_mfma_f32_32x32x16_bf16(akf, aq[ch], s, 0, 0, 0);   \
    }                                                                         \
    __builtin_amdgcn_s_setprio(0);                                            \
    if ((T) + 1 < nt) {                                                       \
      STAGE_TO((BUF) ^ 1);                                                    \
      if ((T) + 2 < nt) LOAD_TILE();                                          \
    }                                                                         \
    const int rel_ = kv0_ + kho - q0w;                                        \
    if (rel_ >= -224 && rel_ <= 224) {                                        \
      _Pragma("unroll")                                                       \
      for (int g = 0; g < 16; g += 2) {                                       \
        const float p0 = __builtin_amdgcn_exp2f(s[g]);                        \
        const float p1 = __builtin_amdgcn_exp2f(s[g + 1]);                    \
        s[g] = p0; s[g + 1] = p1; lsA += p0; lsB += p1;                       \
      }                                                                       \
    } else {                                                                  \
      const int bm_ = rel_ + 4 * hi - c + WIN;                                \
      _Pragma("unroll")                                                       \
      for (int g = 0; g < 16; ++g) {                                          \
        const int ro_ = (g & 3) + 8 * (g >> 2);                               \
        const float p = ((unsigned)(bm_ + ro_) <= 2u * WIN)                   \
                          ? __builtin_amdgcn_exp2f(s[g]) : 0.f;               \
        s[g] = p; if (g & 1) lsB += p; else lsA += p;                         \
      }                                                                       \
    }                                                                         \
    __builtin_amdgcn_s_setprio(1);                                            \
    _Pragma("unroll")                                                         \
    for (int kt = 0; kt < 2; ++kt) {                                          \
      u32x4 pau;                                                              \
      _Pragma("unroll")                                                       \
      for (int p2 = 0; p2 < 4; ++p2)                                          \
        pau[p2] = cvt2(s[kt * 8 + 2 * p2], s[kt * 8 + 2 * p2 + 1]);           \
      const bf16x8 pa = __builtin_bit_cast(bf16x8, pau);                      \
      bf16x8 bv0 = *(const bf16x8*)&vrd[(BUF) * VHALF + kt * 16];             \
      acc0 = __builtin_amdgcn_mfma_f32_32x32x16_bf16(pa, bv0, acc0, 0, 0, 0); \
      bf16x8 bv1 = *(const bf16x8*)&vrd[(BUF) * VHALF + kt * 16 + 32 * VSTR]; \
      acc1 = __builtin_amdgcn_mfma_f32_32x32x16_bf16(pa, bv1, acc1, 0, 0, 0); \
    }                                                                         \
    __builtin_amdgcn_s_setprio(0);                                            \
    if ((T) + 1 < nt) PUB_BARRIER();                                          \
  } while (0)

  // prologue: stage tile 0 into buf 0, prefetch tile 1 (loads ride across barrier)
  LOAD_TILE();
  STAGE_TO(0);
  LOAD_TILE();
  PUB_BARRIER();

  for (int t = 0; t < nt; t += 2) {   // nt even: buffer index is compile-time
    TILE_BODY(t, 0);
    TILE_BODY(t + 1, 1);
  }

  // ---- epilogue: merge key halves; overlay on dead K/V LDS ----
  float lsum = lsA + lsB;
  lsum += __shfl_xor(lsum, 32);
  __syncthreads();
  float* o_mrg = (float*)smem;                   // [4][32][64]
  float* l_par = (float*)(smem + LPAR_OFF);      // [2][4][32]
  if (hi == 0) l_par[(kh * 4 + qg) * 32 + c] = lsum;
  if (kh == 0) {
    #pragma unroll
    for (int g = 0; g < 16; ++g) {
      const int qrow = (g & 3) + 8 * (g >> 2) + 4 * hi;
      o_mrg[(qg * 32 + qrow) * HEAD_D + c]      = acc0[g];
      o_mrg[(qg * 32 + qrow) * HEAD_D + 32 + c] = acc1[g];
    }
  }
  __syncthreads();
  if (kh == 1) {
    if (hi == 0) l_par[qg * 32 + c] = 1.0f / (l_par[qg * 32 + c] + l_par[(4 + qg) * 32 + c]);
    __asm__ volatile("s_waitcnt lgkmcnt(0)" ::: "memory");
    __builtin_amdgcn_sched_barrier(0);
    #pragma unroll
    for (int g = 0; g < 16; ++g) {
      const int qrow = (g & 3) + 8 * (g >> 2) + 4 * hi;
      const float iv = l_par[qg * 32 + qrow];
      float* orow = Op + (size_t)(q0w + qrow) * HEAD_D;
      orow[c]      = (o_mrg[(qg * 32 + qrow) * HEAD_D + c]      + acc0[g]) * iv;
      orow[32 + c] = (o_mrg[(qg * 32 + qrow) * HEAD_D + 32 + c] + acc1[g]) * iv;
    }
  }
}

extern "C" void kernel_launch(void* const* d_in, const int* in_sizes, int n_in,
                              void* d_out, int out_size, void* d_ws, size_t ws_size,
                              hipStream_t stream) {
  const float* q = (const float*)d_in[0];
  const float* k = (const float*)d_in[1];
  const float* v = (const float*)d_in[2];
  float* o = (float*)d_out;
  const int blocks = 2 * 16 * (S_LEN / QBLK);  // 1024
  swa_fwd<<<dim3(blocks), dim3(512), 0, stream>>>(q, k, v, o);
}